// Round 9
// baseline (171.069 us; speedup 1.0000x reference)
//
#include <hip/hip_runtime.h>
#include <cstddef>

#define S_LEN 4096
#define C_DIM 256
#define NHEADS 8
#define HDIM 32

typedef __attribute__((ext_vector_type(8))) _Float16 half8;
typedef __attribute__((ext_vector_type(4))) _Float16 half4;
typedef __attribute__((ext_vector_type(2))) _Float16 h2t;
typedef __attribute__((ext_vector_type(2))) __fp16 fp16x2;
typedef __attribute__((ext_vector_type(4))) float floatx4;

// scale * log2(e) folded into W_q and bias_q at prep time
#define SC2F ((float)(0.17677669529663687 * 1.4426950408889634))

// ---------------------------------------------------------------- prep + GN stats (fused)
__global__ __launch_bounds__(256) void prep_stats(
    const float* __restrict__ qkv_w, const float* __restrict__ proj_w,
    const float* __restrict__ qkv_b, const float* __restrict__ x,
    _Float16* __restrict__ wq, _Float16* __restrict__ wp,
    float* __restrict__ qbias, float* __restrict__ gstat)
{
  const int blk = blockIdx.x;
  const int tid = threadIdx.x;
  if (blk < 64) {
    __shared__ float red[2][4];
    const int g = blk & 31, b = blk >> 5;
    const float* xb = x + ((size_t)b * C_DIM + g * 8) * S_LEN;
    const float4* x4 = (const float4*)xb;
    float sum = 0.f, sumsq = 0.f;
    for (int i = tid; i < 8192; i += 256) {
      float4 v = x4[i];
      sum += v.x + v.y + v.z + v.w;
      sumsq += v.x * v.x + v.y * v.y + v.z * v.z + v.w * v.w;
    }
    for (int off = 1; off < 64; off <<= 1) {
      sum += __shfl_xor(sum, off, 64);
      sumsq += __shfl_xor(sumsq, off, 64);
    }
    const int wv = tid >> 6, lane = tid & 63;
    if (lane == 0) { red[0][wv] = sum; red[1][wv] = sumsq; }
    __syncthreads();
    if (tid == 0) {
      float s = red[0][0] + red[0][1] + red[0][2] + red[0][3];
      float sq = red[1][0] + red[1][1] + red[1][2] + red[1][3];
      float mean = s * (1.f / 32768.f);
      float var = sq * (1.f / 32768.f) - mean * mean;
      gstat[((size_t)b * 32 + g) * 2 + 0] = mean;
      gstat[((size_t)b * 32 + g) * 2 + 1] = rsqrtf(var + 1e-6f);
    }
  } else {
    int idx = (blk - 64) * 256 + tid;
    if (idx < 768 * 256) {
      float v = qkv_w[idx];
      if (idx < 256 * 256) v *= SC2F;          // q rows
      wq[idx] = (_Float16)v;
    } else if (idx < 768 * 256 + 256 * 256) {
      int i = idx - 768 * 256;
      wp[i] = (_Float16)proj_w[i];
    } else if (idx < 768 * 256 + 256 * 256 + 768) {
      int i = idx - (768 * 256 + 256 * 256);
      float bv = qkv_b[i];
      if (i < 256) bv *= SC2F;
      qbias[i] = bv;
    }
  }
}

// ---------------------------------------------------------------- QKV GEMM + inline GN
__global__ __launch_bounds__(256) void qkv_gn_gemm(
    const _Float16* __restrict__ W, const float* __restrict__ bias,
    const float* __restrict__ x, const float* __restrict__ gamma,
    const float* __restrict__ beta, const float* __restrict__ gstat,
    _Float16* __restrict__ qo, _Float16* __restrict__ ko_,
    _Float16* __restrict__ vo)
{
  __shared__ __align__(16) _Float16 Ld[64 * 264];   // [s][c], stride 264
  const int tid = threadIdx.x;
  const int b = blockIdx.z;
  const int s0 = blockIdx.y * 64;

  {  // ---- inline GN apply: x (c,s) -> Ld[s][c] f16
    const int c0 = (tid & 127) * 2, c1 = c0 + 1;
    const int sh = tid >> 7;                         // s-half 0/1
    const int g = c0 >> 3;
    const float mean = gstat[((size_t)b * 32 + g) * 2 + 0];
    const float rstd = gstat[((size_t)b * 32 + g) * 2 + 1];
    const float ga0 = gamma[c0] * rstd, be0 = beta[c0] - mean * ga0;
    const float ga1 = gamma[c1] * rstd, be1 = beta[c1] - mean * ga1;
    const float4* xa = (const float4*)(x + ((size_t)b * C_DIM + c0) * S_LEN + s0 + sh * 32);
    const float4* xc = (const float4*)(x + ((size_t)b * C_DIM + c1) * S_LEN + s0 + sh * 32);
    #pragma unroll
    for (int j = 0; j < 8; ++j) {
      float4 a = xa[j], c = xc[j];
      int sl = sh * 32 + j * 4;
      *(h2t*)&Ld[(sl + 0) * 264 + c0] = (h2t){ (_Float16)(a.x * ga0 + be0), (_Float16)(c.x * ga1 + be1) };
      *(h2t*)&Ld[(sl + 1) * 264 + c0] = (h2t){ (_Float16)(a.y * ga0 + be0), (_Float16)(c.y * ga1 + be1) };
      *(h2t*)&Ld[(sl + 2) * 264 + c0] = (h2t){ (_Float16)(a.z * ga0 + be0), (_Float16)(c.z * ga1 + be1) };
      *(h2t*)&Ld[(sl + 3) * 264 + c0] = (h2t){ (_Float16)(a.w * ga0 + be0), (_Float16)(c.w * ga1 + be1) };
    }
  }
  __syncthreads();

  const int lane = tid & 63, wv = tid >> 6;
  const int m = lane & 15, quad = lane >> 4;
  const int mtb = blockIdx.x * 8 + wv * 2;      // 2 mt tiles per wave
  const _Float16* wrow0 = W + (size_t)((mtb + 0) * 16 + m) * C_DIM + quad * 8;
  const _Float16* wrow1 = W + (size_t)((mtb + 1) * 16 + m) * C_DIM + quad * 8;
  const _Float16* lp = &Ld[m * 264 + quad * 8];

  floatx4 acc[2][4];
  #pragma unroll
  for (int j = 0; j < 2; ++j)
    #pragma unroll
    for (int s = 0; s < 4; ++s) acc[j][s] = (floatx4){0.f,0.f,0.f,0.f};

  #pragma unroll
  for (int k0 = 0; k0 < C_DIM; k0 += 32) {
    half8 b0 = *(const half8*)(lp + k0);
    half8 b1 = *(const half8*)(lp + 16 * 264 + k0);
    half8 b2 = *(const half8*)(lp + 32 * 264 + k0);
    half8 b3 = *(const half8*)(lp + 48 * 264 + k0);
    half8 a0 = *(const half8*)(wrow0 + k0);
    half8 a1 = *(const half8*)(wrow1 + k0);
    acc[0][0] = __builtin_amdgcn_mfma_f32_16x16x32_f16(a0, b0, acc[0][0], 0, 0, 0);
    acc[0][1] = __builtin_amdgcn_mfma_f32_16x16x32_f16(a0, b1, acc[0][1], 0, 0, 0);
    acc[0][2] = __builtin_amdgcn_mfma_f32_16x16x32_f16(a0, b2, acc[0][2], 0, 0, 0);
    acc[0][3] = __builtin_amdgcn_mfma_f32_16x16x32_f16(a0, b3, acc[0][3], 0, 0, 0);
    acc[1][0] = __builtin_amdgcn_mfma_f32_16x16x32_f16(a1, b0, acc[1][0], 0, 0, 0);
    acc[1][1] = __builtin_amdgcn_mfma_f32_16x16x32_f16(a1, b1, acc[1][1], 0, 0, 0);
    acc[1][2] = __builtin_amdgcn_mfma_f32_16x16x32_f16(a1, b2, acc[1][2], 0, 0, 0);
    acc[1][3] = __builtin_amdgcn_mfma_f32_16x16x32_f16(a1, b3, acc[1][3], 0, 0, 0);
  }

  #pragma unroll
  for (int j = 0; j < 2; ++j) {
    const int ob = (mtb + j) * 16 + quad * 4;
    const float bv0 = bias[ob], bv1 = bias[ob + 1],
                bv2 = bias[ob + 2], bv3 = bias[ob + 3];
    #pragma unroll
    for (int sub = 0; sub < 4; ++sub) {
      int s = s0 + sub * 16 + m;
      float v0 = acc[j][sub][0] + bv0, v1 = acc[j][sub][1] + bv1,
            v2 = acc[j][sub][2] + bv2, v3 = acc[j][sub][3] + bv3;
      if (ob < 512) {                       // q or k: (B,NH,S,hd)
        _Float16* dst = (ob < 256) ? qo : ko_;
        int oo = ob & 255, n = oo >> 5, d0 = oo & 31;
        half4 h = { (_Float16)v0, (_Float16)v1, (_Float16)v2, (_Float16)v3 };
        *(half4*)(dst + (((size_t)b * NHEADS + n) * S_LEN + s) * HDIM + d0) = h;
      } else {                              // v: (B,NH,hd,S)
        int oo = ob - 512, n = oo >> 5, d0 = oo & 31;
        _Float16* dst = vo + ((size_t)b * NHEADS + n) * HDIM * S_LEN + s;
        dst[(size_t)(d0 + 0) * S_LEN] = (_Float16)v0;
        dst[(size_t)(d0 + 1) * S_LEN] = (_Float16)v1;
        dst[(size_t)(d0 + 2) * S_LEN] = (_Float16)v2;
        dst[(size_t)(d0 + 3) * S_LEN] = (_Float16)v3;
      }
    }
  }
}

// ---------------------------------------------------------------- Attention
// 8 waves, 16 q/wave, 2-way key split (2048 keys/block). 128-key LDS tiles
// (16 barriers), int4 staging. Vl stride 136 halfs -> vf b64 reads 2-way
// bank aliasing (free). Unnormalized partials (po f16, pl f32).
__global__ __launch_bounds__(512) void attn_kernel(
    const _Float16* __restrict__ q, const _Float16* __restrict__ k,
    const _Float16* __restrict__ v, _Float16* __restrict__ po,
    float* __restrict__ pl)
{
  __shared__ __align__(16) _Float16 Kl[2][128 * 40];   // (kk, d) stride 40
  __shared__ __align__(16) _Float16 Vl[2][32 * 136];   // (d, kk) stride 136
  const int tid = threadIdx.x;
  const int lane = tid & 63, wv = tid >> 6;          // wv 0..7
  const int m = lane & 15, quad = lane >> 4;
  const int n = blockIdx.y, b = blockIdx.z;
  const int qc = blockIdx.x >> 1, kh = blockIdx.x & 1;
  const int q0 = qc * 128 + wv * 16;
  const int bh = b * NHEADS + n;

  const _Float16* qb = q + (size_t)bh * S_LEN * HDIM;
  const _Float16* kb = k + (size_t)bh * S_LEN * HDIM + (size_t)kh * 2048 * HDIM;
  const _Float16* vb = v + (size_t)bh * HDIM * S_LEN + (size_t)kh * 2048;

  // Q B-frag (QK): lane q=m holds d=quad*8+j
  half8 qf = *(const half8*)(qb + (size_t)(q0 + m) * HDIM + quad * 8);

  // staging (512 threads, 16B each): K 128x32 halfs, V 32x128 halfs
  const int krow = tid >> 2, kc = (tid & 3) * 8;
  const int vrow = tid >> 4, vc = (tid & 15) * 8;
  const _Float16* kg = kb + (size_t)krow * HDIM + kc;
  const _Float16* vg = vb + (size_t)vrow * S_LEN + vc;
  const int klds = krow * 40 + kc;
  const int vlds = vrow * 136 + vc;

  int4 kreg = *(const int4*)kg;
  int4 vreg = *(const int4*)vg;
  const _Float16* kgp = kg + 128 * HDIM;
  const _Float16* vgp = vg + 128;

  floatx4 o0 = {0.f,0.f,0.f,0.f}, o1 = o0;   // d-tiles 0/1 for this wave's 16 q
  float l0 = 0.f;
  const fp16x2 one2 = { (__fp16)1.0f, (__fp16)1.0f };

  #pragma unroll 2
  for (int it = 0; it < 16; ++it) {          // 16 x 128 keys = 2048 (half)
    const int bufi = it & 1;
    *(int4*)(&Kl[bufi][klds]) = kreg;
    *(int4*)(&Vl[bufi][vlds]) = vreg;
    kreg = *(const int4*)kgp; kgp += 128 * HDIM;   // unconditional prefetch
    vreg = *(const int4*)vgp; vgp += 128;
    __syncthreads();
    const _Float16* Kb = Kl[bufi];
    const _Float16* Vb = Vl[bufi];
    #pragma unroll
    for (int t = 0; t < 8; ++t) {
      half8 kf = *(const half8*)(Kb + (t * 16 + m) * 40 + quad * 8);
      half4 vf0 = *(const half4*)(Vb + m * 136 + t * 16 + quad * 4);
      half4 vf1 = *(const half4*)(Vb + (16 + m) * 136 + t * 16 + quad * 4);
      floatx4 z = {0.f,0.f,0.f,0.f};
      floatx4 s0 = __builtin_amdgcn_mfma_f32_16x16x32_f16(kf, qf, z, 0, 0, 0);
      float e0 = __builtin_amdgcn_exp2f(s0[0]);
      float e1 = __builtin_amdgcn_exp2f(s0[1]);
      float e2 = __builtin_amdgcn_exp2f(s0[2]);
      float e3 = __builtin_amdgcn_exp2f(s0[3]);
      half4 p0;
      fp16x2 plo = __builtin_amdgcn_cvt_pkrtz(e0, e1);
      fp16x2 phi = __builtin_amdgcn_cvt_pkrtz(e2, e3);
      *(fp16x2*)&p0 = plo;
      *((fp16x2*)&p0 + 1) = phi;
      l0 = __builtin_amdgcn_fdot2(plo, one2, l0, false);
      l0 = __builtin_amdgcn_fdot2(phi, one2, l0, false);
      o0 = __builtin_amdgcn_mfma_f32_16x16x16f16(vf0, p0, o0, 0, 0, 0);
      o1 = __builtin_amdgcn_mfma_f32_16x16x16f16(vf1, p0, o1, 0, 0, 0);
    }
  }
  // l split across 4 quads (keys) -> reduce
  l0 += __shfl_xor(l0, 16, 64);
  l0 += __shfl_xor(l0, 32, 64);
  // partial store (unnormalized): po[kh][bh][q][d] f16, pl[kh][bh*4096+q]
  _Float16* poh = po + (size_t)kh * 2097152 + ((size_t)bh * S_LEN + q0 + m) * HDIM;
  half4 h0 = { (_Float16)o0[0], (_Float16)o0[1], (_Float16)o0[2], (_Float16)o0[3] };
  half4 h1 = { (_Float16)o1[0], (_Float16)o1[1], (_Float16)o1[2], (_Float16)o1[3] };
  *(half4*)(poh + quad * 4) = h0;
  *(half4*)(poh + 16 + quad * 4) = h1;
  if (quad == 0) pl[(size_t)kh * 65536 + (size_t)bh * S_LEN + q0 + m] = l0;
}

// ---------------------------------------------------------------- Proj GEMM (+ fused merge)
// B-frags built on the fly: (po0 + po1) * (1/(l0+l1)). Per k0-iter the head
// n = k0>>5 is compile-time; 32 reciprocals precomputed in registers.
__global__ __launch_bounds__(256) void proj_gemm(
    const _Float16* __restrict__ W, const float* __restrict__ bias,
    const _Float16* __restrict__ po, const float* __restrict__ pl,
    const float* __restrict__ x, float* __restrict__ out)
{
  const int tid = threadIdx.x;
  const int lane = tid & 63, wv = tid >> 6;
  const int m = lane & 15, quad = lane >> 4;
  const int mt = blockIdx.x * 4 + wv;  // 0..15
  const int s0 = blockIdx.y * 64;
  const int b = blockIdx.z;
  const int row = mt * 16 + m;

  float inv[8][4];
  #pragma unroll
  for (int n = 0; n < 8; ++n) {
    #pragma unroll
    for (int sub = 0; sub < 4; ++sub) {
      size_t idx = ((size_t)(b * NHEADS + n)) * S_LEN + s0 + sub * 16 + m;
      inv[n][sub] = 1.f / (pl[idx] + pl[65536 + idx]);
    }
  }

  const _Float16* wrow = W + (size_t)row * C_DIM + quad * 8;
  floatx4 acc0 = {0.f,0.f,0.f,0.f}, acc1 = acc0, acc2 = acc0, acc3 = acc0;
  #pragma unroll
  for (int k0 = 0; k0 < C_DIM; k0 += 32) {
    const int n = k0 >> 5;
    const int d0 = quad * 8;
    half8 bf[4];
    #pragma unroll
    for (int sub = 0; sub < 4; ++sub) {
      size_t idx = (((size_t)(b * NHEADS + n)) * S_LEN + s0 + sub * 16 + m) * HDIM + d0;
      half8 a = *(const half8*)(po + idx);
      half8 c = *(const half8*)(po + 2097152 + idx);
      _Float16 iv = (_Float16)inv[n][sub];
      bf[sub] = (a + c) * iv;
    }
    half8 af = *(const half8*)(wrow + k0);
    acc0 = __builtin_amdgcn_mfma_f32_16x16x32_f16(af, bf[0], acc0, 0, 0, 0);
    acc1 = __builtin_amdgcn_mfma_f32_16x16x32_f16(af, bf[1], acc1, 0, 0, 0);
    acc2 = __builtin_amdgcn_mfma_f32_16x16x32_f16(af, bf[2], acc2, 0, 0, 0);
    acc3 = __builtin_amdgcn_mfma_f32_16x16x32_f16(af, bf[3], acc3, 0, 0, 0);
  }
  floatx4 accs[4] = {acc0, acc1, acc2, acc3};
  #pragma unroll
  for (int sub = 0; sub < 4; ++sub) {
    int s = s0 + sub * 16 + m;
    #pragma unroll
    for (int r = 0; r < 4; ++r) {
      int c = mt * 16 + quad * 4 + r;
      size_t idx = ((size_t)b * C_DIM + c) * S_LEN + s;
      out[idx] = x[idx] + accs[sub][r] + bias[c];
    }
  }
}

// ---------------------------------------------------------------- launch
extern "C" void kernel_launch(void* const* d_in, const int* in_sizes, int n_in,
                              void* d_out, int out_size, void* d_ws, size_t ws_size,
                              hipStream_t stream) {
  const float* x        = (const float*)d_in[0];
  const float* gn_gamma = (const float*)d_in[1];
  const float* gn_beta  = (const float*)d_in[2];
  const float* qkv_w    = (const float*)d_in[3];
  const float* qkv_b    = (const float*)d_in[4];
  const float* proj_w   = (const float*)d_in[5];
  const float* proj_b   = (const float*)d_in[6];
  float* out = (float*)d_out;

  const size_t n1 = (size_t)2 * S_LEN * C_DIM;   // 2M elems = 4 MB f16
  char* ws = (char*)d_ws;
  _Float16* qx  = (_Float16*)ws;                 // (B,NH,S,hd)
  _Float16* kx  = qx + n1;                       // (B,NH,S,hd)
  _Float16* vx  = kx + n1;                       // (B,NH,hd,S)
  _Float16* wq  = vx + n1;                       // 768x256 f16
  _Float16* wp  = wq + 768 * 256;                // 256x256 f16
  float*    qbias = (float*)(wp + 256 * 256);    // 768 f32
  float*    gstat = qbias + 768;                 // 128 f32
  _Float16* po  = (_Float16*)(gstat + 128);      // 2 x 2M f16 = 8 MB
  float*    pl  = (float*)(po + 2 * n1);         // 2 x 64K f32 = 512 KB

  prep_stats<<<1091, 256, 0, stream>>>(qkv_w, proj_w, qkv_b, x, wq, wp, qbias, gstat);
  qkv_gn_gemm<<<dim3(6, 64, 2), 256, 0, stream>>>(wq, qbias, x, gn_gamma, gn_beta, gstat, qx, kx, vx);
  attn_kernel<<<dim3(64, 8, 2), 512, 0, stream>>>(qx, kx, vx, po, pl);
  proj_gemm<<<dim3(4, 64, 2), 256, 0, stream>>>(wp, proj_b, po, pl, x, out);
}